// Round 1
// baseline (477.480 us; speedup 1.0000x reference)
//
#include <hip/hip_runtime.h>

// Problem constants
#define DD   256
#define SEQ  128
#define NB   32
#define VOC  32000
#define ROWS (NB * SEQ)   // 4096
#define KK   512          // 2*D (real|imag concat)

// Workspace layout (bytes):
//  Wb   bf16 [32000][512]          32,768,000
//  bias f32  [32000]                  128,000
//  Sb   f32  [4096][512]            8,388,608
//  Qb   f32  [4096][512]            8,388,608
//  Kb   f32  [4096][512]            8,388,608
//  Vb   f32  [4096][512]            8,388,608
//  S2   f32  [4096][512]            8,388,608
//  X    bf16 [4096][512]            4,194,304
//  total ~79.0 MB

typedef __attribute__((ext_vector_type(8))) short short8;
typedef __attribute__((ext_vector_type(4))) float f32x4;

__device__ inline unsigned short f2bf(float f) {
  unsigned int u = __float_as_uint(f);
  u += 0x7FFF + ((u >> 16) & 1);   // RNE
  return (unsigned short)(u >> 16);
}

// K0: pack W rows = [wr | wi] -> bf16, bias = br + bi
__global__ __launch_bounds__(256) void k_prep(
    const float* __restrict__ wr, const float* __restrict__ wi,
    const float* __restrict__ br, const float* __restrict__ bi,
    unsigned short* __restrict__ Wb, float* __restrict__ bias) {
  int idx = blockIdx.x * 256 + threadIdx.x;   // one 4-elem chunk
  int v = idx >> 7, c = idx & 127;
  const float* src = (c < 64) ? (wr + (size_t)v * DD + c * 4)
                              : (wi + (size_t)v * DD + (c - 64) * 4);
  float4 f = *(const float4*)src;
  ushort4 o;
  o.x = f2bf(f.x); o.y = f2bf(f.y); o.z = f2bf(f.z); o.w = f2bf(f.w);
  *(ushort4*)(Wb + (size_t)v * KK + c * 4) = o;
  if (c == 0) bias[v] = br[v] + bi[v];
}

// K1: mag = tanh(emb[x]); state/q/k/v real+imag parts (rot by constant phase)
__global__ __launch_bounds__(256) void k_embed(
    const int* __restrict__ x, const float* __restrict__ emb,
    const float* __restrict__ qrot, const float* __restrict__ krot,
    const float* __restrict__ vrot,
    float* __restrict__ Sb, float* __restrict__ Qb,
    float* __restrict__ Kb, float* __restrict__ Vb) {
  int row = blockIdx.x;          // b*SEQ + s
  int s = row & (SEQ - 1);
  int d = threadIdx.x;
  int tok = x[row];
  float m = tanhf(emb[(size_t)tok * DD + d]);
  float freq = expf(-(float)d * (9.210340371976184f / 256.f)); // 10000^(-d/256)
  float p = (float)s * freq * 3.14159265358979f;
  float sn, cs;
  size_t base = (size_t)row * KK + d;
  sincosf(p, &sn, &cs);             Sb[base] = m * cs; Sb[base + DD] = m * sn;
  float a;
  a = p + qrot[d]; sincosf(a, &sn, &cs); Qb[base] = m * cs; Qb[base + DD] = m * sn;
  a = p + krot[d]; sincosf(a, &sn, &cs); Kb[base] = m * cs; Kb[base + DD] = m * sn;
  a = p + vrot[d]; sincosf(a, &sn, &cs); Vb[base] = m * cs; Vb[base + DD] = m * sn;
}

// K2: one block per (b,s): causal logits (dot*0.5), softmax, PV, residual add
__global__ __launch_bounds__(256) void k_attn(
    const float* __restrict__ Qb, const float* __restrict__ Kb,
    const float* __restrict__ Vb, const float* __restrict__ Sb,
    float* __restrict__ S2) {
  int row = blockIdx.x;
  int b = row >> 7, s = row & 127;
  int tid = threadIdx.x;
  __shared__ __align__(16) float q[KK];
  __shared__ float w[SEQ];
  __shared__ float smax, ssum;
  q[tid] = Qb[(size_t)row * KK + tid];
  q[tid + 256] = Qb[(size_t)row * KK + 256 + tid];
  __syncthreads();
  int t = tid >> 1, half = tid & 1;
  const float4* q4 = (const float4*)(q + half * 256);
  const float4* k4 = (const float4*)(Kb + ((size_t)(b * SEQ + t)) * KK + half * 256);
  float acc = 0.f;
  if (t <= s) {
#pragma unroll 4
    for (int i = 0; i < 64; ++i) {
      float4 qa = q4[i], ka = k4[i];
      acc += qa.x * ka.x + qa.y * ka.y + qa.z * ka.z + qa.w * ka.w;
    }
  }
  acc += __shfl_xor(acc, 1);
  if (half == 0) w[t] = (t <= s) ? acc * 0.5f : -INFINITY;
  __syncthreads();
  if (tid < 64) {
    float m2 = fmaxf(w[tid], w[tid + 64]);
    for (int o = 32; o; o >>= 1) m2 = fmaxf(m2, __shfl_xor(m2, o));
    if (tid == 0) smax = m2;
  }
  __syncthreads();
  if (tid < 128) w[tid] = expf(w[tid] - smax);
  __syncthreads();
  if (tid < 64) {
    float s2 = w[tid] + w[tid + 64];
    for (int o = 32; o; o >>= 1) s2 += __shfl_xor(s2, o);
    if (tid == 0) ssum = s2;
  }
  __syncthreads();
  float inv = 1.f / ssum;
  float o0 = 0.f, o1 = 0.f;
  const float* vb = Vb + (size_t)(b * SEQ) * KK;
  int nt = s + 1;
  for (int tt = 0; tt < nt; ++tt) {
    float wt = w[tt];
    o0 += wt * vb[(size_t)tt * KK + tid];
    o1 += wt * vb[(size_t)tt * KK + 256 + tid];
  }
  size_t base = (size_t)row * KK + tid;
  S2[base] = Sb[base] + o0 * inv;
  S2[base + 256] = Sb[base + 256] + o1 * inv;
}

// K3: complex FF (state @ (ffr + i*ffi)), complex_norm, cast to bf16 X
__global__ __launch_bounds__(256) void k_ffnorm(
    const float* __restrict__ S2, const float* __restrict__ ffr,
    const float* __restrict__ ffi, unsigned short* __restrict__ X) {
  int row0 = blockIdx.x * 4;
  int d = threadIdx.x;
  __shared__ __align__(16) float in[4][KK];
  __shared__ float mg[4][DD];
  __shared__ float stats[8];
#pragma unroll
  for (int i = 0; i < 8; ++i)
    ((float*)in)[i * 256 + d] = S2[(size_t)row0 * KK + i * 256 + d];
  __syncthreads();
  float nr[4] = {0, 0, 0, 0}, ni[4] = {0, 0, 0, 0};
  for (int e = 0; e < DD; ++e) {
    float fr = ffr[e * DD + d];
    float fi = ffi[e * DD + d];
#pragma unroll
    for (int r = 0; r < 4; ++r) {
      float a = in[r][e], c = in[r][DD + e];
      nr[r] += a * fr - c * fi;
      ni[r] += a * fi + c * fr;
    }
  }
#pragma unroll
  for (int r = 0; r < 4; ++r) mg[r][d] = sqrtf(nr[r] * nr[r] + ni[r] * ni[r]);
  __syncthreads();
  int wv = d >> 6, ln = d & 63;
  float s0 = mg[wv][ln] + mg[wv][ln + 64] + mg[wv][ln + 128] + mg[wv][ln + 192];
  for (int o = 32; o; o >>= 1) s0 += __shfl_xor(s0, o);
  float mean = s0 * (1.f / 256.f);
  float var = 0.f;
#pragma unroll
  for (int k = 0; k < 4; ++k) { float t2 = mg[wv][ln + k * 64] - mean; var += t2 * t2; }
  for (int o = 32; o; o >>= 1) var += __shfl_xor(var, o);
  if (ln == 0) { stats[wv * 2] = mean; stats[wv * 2 + 1] = sqrtf(var * (1.f / 255.f)); }
  __syncthreads();
#pragma unroll
  for (int r = 0; r < 4; ++r) {
    float mean2 = stats[r * 2], stdv = stats[r * 2 + 1];
    float mag = mg[r][d];
    float norm = (mag - mean2) / (stdv + 1e-5f);
    float sc = tanhf(norm) / (mag + 1e-5f);
    size_t base = (size_t)(row0 + r) * KK + d;
    X[base] = f2bf(nr[r] * sc);
    X[base + DD] = f2bf(ni[r] * sc);
  }
}

// K4: logits[4096][32000] = X[4096][512] * Wb[32000][512]^T + bias
// 128x128 tile, BK=64, 4 waves, 16x16x32 bf16 MFMA
__global__ __launch_bounds__(256) void k_gemm(
    const unsigned short* __restrict__ X, const unsigned short* __restrict__ Wb,
    const float* __restrict__ bias, float* __restrict__ out) {
  __shared__ __align__(16) unsigned short At[128 * 64];
  __shared__ __align__(16) unsigned short Bt[128 * 64];
  int tid = threadIdx.x;
  int lane = tid & 63, wave = tid >> 6;
  int wr = wave >> 1, wc = wave & 1;
  size_t rowA0 = (size_t)blockIdx.y * 128;   // M tile
  size_t rowB0 = (size_t)blockIdx.x * 128;   // N tile
  f32x4 acc[4][4] = {};
  for (int kt = 0; kt < 8; ++kt) {
    const int k0 = kt * 64;
#pragma unroll
    for (int i = 0; i < 4; ++i) {
      int chunk = i * 256 + tid;
      int r = chunk >> 3, k8 = chunk & 7;
      *(uint4*)&At[chunk * 8] = *(const uint4*)&X[(rowA0 + r) * KK + k0 + k8 * 8];
      *(uint4*)&Bt[chunk * 8] = *(const uint4*)&Wb[(rowB0 + r) * KK + k0 + k8 * 8];
    }
    __syncthreads();
#pragma unroll
    for (int ks = 0; ks < 2; ++ks) {
      short8 a[4], bb[4];
#pragma unroll
      for (int mb = 0; mb < 4; ++mb)
        a[mb] = *(const short8*)&At[(wr * 64 + mb * 16 + (lane & 15)) * 64 + ks * 32 + (lane >> 4) * 8];
#pragma unroll
      for (int nb = 0; nb < 4; ++nb)
        bb[nb] = *(const short8*)&Bt[(wc * 64 + nb * 16 + (lane & 15)) * 64 + ks * 32 + (lane >> 4) * 8];
#pragma unroll
      for (int mb = 0; mb < 4; ++mb)
#pragma unroll
        for (int nb = 0; nb < 4; ++nb)
          acc[mb][nb] = __builtin_amdgcn_mfma_f32_16x16x32_bf16(a[mb], bb[nb], acc[mb][nb], 0, 0, 0);
    }
    __syncthreads();
  }
  int cr = lane >> 4, cc = lane & 15;
#pragma unroll
  for (int nb = 0; nb < 4; ++nb) {
    size_t col = rowB0 + wc * 64 + nb * 16 + cc;
    float bv = bias[col];
#pragma unroll
    for (int mb = 0; mb < 4; ++mb) {
#pragma unroll
      for (int j = 0; j < 4; ++j) {
        size_t rowc = rowA0 + wr * 64 + mb * 16 + cr * 4 + j;
        out[rowc * VOC + col] = acc[mb][nb][j] + bv;
      }
    }
  }
}

extern "C" void kernel_launch(void* const* d_in, const int* in_sizes, int n_in,
                              void* d_out, int out_size, void* d_ws, size_t ws_size,
                              hipStream_t stream) {
  const int* x      = (const int*)d_in[0];
  const float* emb  = (const float*)d_in[1];
  const float* qrot = (const float*)d_in[2];
  const float* krot = (const float*)d_in[3];
  const float* vrot = (const float*)d_in[4];
  const float* ffr  = (const float*)d_in[5];
  const float* ffi  = (const float*)d_in[6];
  const float* wr   = (const float*)d_in[7];
  const float* br   = (const float*)d_in[8];
  const float* wi   = (const float*)d_in[9];
  const float* bi   = (const float*)d_in[10];
  float* out = (float*)d_out;
  char* ws = (char*)d_ws;

  unsigned short* Wb = (unsigned short*)ws;                 // 32,768,000 B
  float* bias = (float*)(ws + 32768000);                    //    128,000 B
  float* Sb = (float*)(ws + 32896000);
  float* Qb = Sb + (size_t)ROWS * KK;
  float* Kb = Qb + (size_t)ROWS * KK;
  float* Vb = Kb + (size_t)ROWS * KK;
  float* S2 = Vb + (size_t)ROWS * KK;
  unsigned short* X = (unsigned short*)(S2 + (size_t)ROWS * KK);

  k_prep<<<dim3(VOC * 128 / 256), dim3(256), 0, stream>>>(wr, wi, br, bi, Wb, bias);
  k_embed<<<dim3(ROWS), dim3(256), 0, stream>>>(x, emb, qrot, krot, vrot, Sb, Qb, Kb, Vb);
  k_attn<<<dim3(ROWS), dim3(256), 0, stream>>>(Qb, Kb, Vb, Sb, S2);
  k_ffnorm<<<dim3(ROWS / 4), dim3(256), 0, stream>>>(S2, ffr, ffi, X);
  k_gemm<<<dim3(VOC / 128, ROWS / 128), dim3(256), 0, stream>>>(X, Wb, bias, out);
}

// Round 2
// 476.701 us; speedup vs baseline: 1.0016x; 1.0016x over previous
//
#include <hip/hip_runtime.h>

// Problem constants
#define DD   256
#define SEQ  128
#define NB   32
#define VOC  32000
#define ROWS (NB * SEQ)   // 4096
#define KK   512          // 2*D (real|imag concat)

typedef __attribute__((ext_vector_type(8))) short short8;
typedef __attribute__((ext_vector_type(4))) float f32x4;

__device__ inline unsigned short f2bf(float f) {
  unsigned int u = __float_as_uint(f);
  u += 0x7FFF + ((u >> 16) & 1);   // RNE
  return (unsigned short)(u >> 16);
}

__device__ inline void gload16(const void* g, void* l) {
  __builtin_amdgcn_global_load_lds(
      (const __attribute__((address_space(1))) void*)g,
      (__attribute__((address_space(3))) void*)l, 16, 0, 0);
}

// K0: pack W rows = [wr | wi] -> bf16, bias = br + bi
__global__ __launch_bounds__(256) void k_prep(
    const float* __restrict__ wr, const float* __restrict__ wi,
    const float* __restrict__ br, const float* __restrict__ bi,
    unsigned short* __restrict__ Wb, float* __restrict__ bias) {
  int idx = blockIdx.x * 256 + threadIdx.x;   // one 4-elem chunk
  int v = idx >> 7, c = idx & 127;
  const float* src = (c < 64) ? (wr + (size_t)v * DD + c * 4)
                              : (wi + (size_t)v * DD + (c - 64) * 4);
  float4 f = *(const float4*)src;
  ushort4 o;
  o.x = f2bf(f.x); o.y = f2bf(f.y); o.z = f2bf(f.z); o.w = f2bf(f.w);
  *(ushort4*)(Wb + (size_t)v * KK + c * 4) = o;
  if (c == 0) bias[v] = br[v] + bi[v];
}

// K1: mag = tanh(emb[x]); state/q/k/v real+imag parts (rot by constant phase)
__global__ __launch_bounds__(256) void k_embed(
    const int* __restrict__ x, const float* __restrict__ emb,
    const float* __restrict__ qrot, const float* __restrict__ krot,
    const float* __restrict__ vrot,
    float* __restrict__ Sb, float* __restrict__ Qb,
    float* __restrict__ Kb, float* __restrict__ Vb) {
  int row = blockIdx.x;          // b*SEQ + s
  int s = row & (SEQ - 1);
  int d = threadIdx.x;
  int tok = x[row];
  float m = tanhf(emb[(size_t)tok * DD + d]);
  float freq = expf(-(float)d * (9.210340371976184f / 256.f)); // 10000^(-d/256)
  float p = (float)s * freq * 3.14159265358979f;
  float sn, cs;
  size_t base = (size_t)row * KK + d;
  sincosf(p, &sn, &cs);             Sb[base] = m * cs; Sb[base + DD] = m * sn;
  float a;
  a = p + qrot[d]; sincosf(a, &sn, &cs); Qb[base] = m * cs; Qb[base + DD] = m * sn;
  a = p + krot[d]; sincosf(a, &sn, &cs); Kb[base] = m * cs; Kb[base + DD] = m * sn;
  a = p + vrot[d]; sincosf(a, &sn, &cs); Vb[base] = m * cs; Vb[base + DD] = m * sn;
}

// K2: one block per (b,s): causal logits (dot*0.5), softmax, PV, residual add
__global__ __launch_bounds__(256) void k_attn(
    const float* __restrict__ Qb, const float* __restrict__ Kb,
    const float* __restrict__ Vb, const float* __restrict__ Sb,
    float* __restrict__ S2) {
  int row = blockIdx.x;
  int b = row >> 7, s = row & 127;
  int tid = threadIdx.x;
  __shared__ __align__(16) float q[KK];
  __shared__ float w[SEQ];
  __shared__ float smax, ssum;
  q[tid] = Qb[(size_t)row * KK + tid];
  q[tid + 256] = Qb[(size_t)row * KK + 256 + tid];
  __syncthreads();
  int t = tid >> 1, half = tid & 1;
  const float4* q4 = (const float4*)(q + half * 256);
  const float4* k4 = (const float4*)(Kb + ((size_t)(b * SEQ + t)) * KK + half * 256);
  float acc = 0.f;
  if (t <= s) {
#pragma unroll 4
    for (int i = 0; i < 64; ++i) {
      float4 qa = q4[i], ka = k4[i];
      acc += qa.x * ka.x + qa.y * ka.y + qa.z * ka.z + qa.w * ka.w;
    }
  }
  acc += __shfl_xor(acc, 1);
  if (half == 0) w[t] = (t <= s) ? acc * 0.5f : -INFINITY;
  __syncthreads();
  if (tid < 64) {
    float m2 = fmaxf(w[tid], w[tid + 64]);
    for (int o = 32; o; o >>= 1) m2 = fmaxf(m2, __shfl_xor(m2, o));
    if (tid == 0) smax = m2;
  }
  __syncthreads();
  if (tid < 128) w[tid] = expf(w[tid] - smax);
  __syncthreads();
  if (tid < 64) {
    float s2 = w[tid] + w[tid + 64];
    for (int o = 32; o; o >>= 1) s2 += __shfl_xor(s2, o);
    if (tid == 0) ssum = s2;
  }
  __syncthreads();
  float inv = 1.f / ssum;
  float o0 = 0.f, o1 = 0.f;
  const float* vb = Vb + (size_t)(b * SEQ) * KK;
  int nt = s + 1;
  for (int tt = 0; tt < nt; ++tt) {
    float wt = w[tt];
    o0 += wt * vb[(size_t)tt * KK + tid];
    o1 += wt * vb[(size_t)tt * KK + 256 + tid];
  }
  size_t base = (size_t)row * KK + tid;
  S2[base] = Sb[base] + o0 * inv;
  S2[base + 256] = Sb[base + 256] + o1 * inv;
}

// K3: complex FF (state @ (ffr + i*ffi)), complex_norm, cast to bf16 X
__global__ __launch_bounds__(256) void k_ffnorm(
    const float* __restrict__ S2, const float* __restrict__ ffr,
    const float* __restrict__ ffi, unsigned short* __restrict__ X) {
  int row0 = blockIdx.x * 4;
  int d = threadIdx.x;
  __shared__ __align__(16) float in[4][KK];
  __shared__ float mg[4][DD];
  __shared__ float stats[8];
#pragma unroll
  for (int i = 0; i < 8; ++i)
    ((float*)in)[i * 256 + d] = S2[(size_t)row0 * KK + i * 256 + d];
  __syncthreads();
  float nr[4] = {0, 0, 0, 0}, ni[4] = {0, 0, 0, 0};
  for (int e = 0; e < DD; ++e) {
    float fr = ffr[e * DD + d];
    float fi = ffi[e * DD + d];
#pragma unroll
    for (int r = 0; r < 4; ++r) {
      float a = in[r][e], c = in[r][DD + e];
      nr[r] += a * fr - c * fi;
      ni[r] += a * fi + c * fr;
    }
  }
#pragma unroll
  for (int r = 0; r < 4; ++r) mg[r][d] = sqrtf(nr[r] * nr[r] + ni[r] * ni[r]);
  __syncthreads();
  int wv = d >> 6, ln = d & 63;
  float s0 = mg[wv][ln] + mg[wv][ln + 64] + mg[wv][ln + 128] + mg[wv][ln + 192];
  for (int o = 32; o; o >>= 1) s0 += __shfl_xor(s0, o);
  float mean = s0 * (1.f / 256.f);
  float var = 0.f;
#pragma unroll
  for (int k = 0; k < 4; ++k) { float t2 = mg[wv][ln + k * 64] - mean; var += t2 * t2; }
  for (int o = 32; o; o >>= 1) var += __shfl_xor(var, o);
  if (ln == 0) { stats[wv * 2] = mean; stats[wv * 2 + 1] = sqrtf(var * (1.f / 255.f)); }
  __syncthreads();
#pragma unroll
  for (int r = 0; r < 4; ++r) {
    float mean2 = stats[r * 2], stdv = stats[r * 2 + 1];
    float mag = mg[r][d];
    float norm = (mag - mean2) / (stdv + 1e-5f);
    float sc = tanhf(norm) / (mag + 1e-5f);
    size_t base = (size_t)(row0 + r) * KK + d;
    X[base] = f2bf(nr[r] * sc);
    X[base + DD] = f2bf(ni[r] * sc);
  }
}

// K4: logits[4096][32000] = X[4096][512] * Wb[32000][512]^T + bias
// 128x128 tile, BK=64, 4 waves, 16x16x32 bf16 MFMA, global_load_lds staging
__global__ __launch_bounds__(256) void k_gemm(
    const unsigned short* __restrict__ X, const unsigned short* __restrict__ Wb,
    const float* __restrict__ bias, float* __restrict__ out) {
  __shared__ __align__(16) unsigned short At[128 * 64];
  __shared__ __align__(16) unsigned short Bt[128 * 64];
  int tid = threadIdx.x;
  int lane = tid & 63, wave = tid >> 6;
  int wr = wave >> 1, wc = wave & 1;
  size_t rowA0 = (size_t)blockIdx.y * 128;   // M tile
  size_t rowB0 = (size_t)blockIdx.x * 128;   // N tile
  // staging geometry: chunk = wave*4+i (16 chunks); chunk covers 8 rows
  // lane l: row = chunk*8 + l/8, kofs = (l%8)*8  -> LDS elem chunk*512 + l*8
  int srow = lane >> 3, skofs = (lane & 7) * 8;
  f32x4 acc[4][4] = {};
  for (int kt = 0; kt < 8; ++kt) {
    const int k0 = kt * 64;
#pragma unroll
    for (int i = 0; i < 4; ++i) {
      int chunk = wave * 4 + i;
      int r = chunk * 8 + srow;
      gload16(&X [(rowA0 + r) * KK + k0 + skofs], &At[chunk * 512]);
      gload16(&Wb[(rowB0 + r) * KK + k0 + skofs], &Bt[chunk * 512]);
    }
    __syncthreads();
#pragma unroll
    for (int ks = 0; ks < 2; ++ks) {
      short8 a[4], bb[4];
#pragma unroll
      for (int mb = 0; mb < 4; ++mb)
        a[mb] = *(const short8*)&At[(wr * 64 + mb * 16 + (lane & 15)) * 64 + ks * 32 + (lane >> 4) * 8];
#pragma unroll
      for (int nb = 0; nb < 4; ++nb)
        bb[nb] = *(const short8*)&Bt[(wc * 64 + nb * 16 + (lane & 15)) * 64 + ks * 32 + (lane >> 4) * 8];
#pragma unroll
      for (int mb = 0; mb < 4; ++mb)
#pragma unroll
        for (int nb = 0; nb < 4; ++nb)
          acc[mb][nb] = __builtin_amdgcn_mfma_f32_16x16x32_bf16(a[mb], bb[nb], acc[mb][nb], 0, 0, 0);
    }
    __syncthreads();
  }
  int cr = lane >> 4, cc = lane & 15;
#pragma unroll
  for (int nb = 0; nb < 4; ++nb) {
    size_t col = rowB0 + wc * 64 + nb * 16 + cc;
    float bv = bias[col];
#pragma unroll
    for (int mb = 0; mb < 4; ++mb) {
#pragma unroll
      for (int j = 0; j < 4; ++j) {
        size_t rowc = rowA0 + wr * 64 + mb * 16 + cr * 4 + j;
        out[rowc * VOC + col] = acc[mb][nb][j] + bv;
      }
    }
  }
}

extern "C" void kernel_launch(void* const* d_in, const int* in_sizes, int n_in,
                              void* d_out, int out_size, void* d_ws, size_t ws_size,
                              hipStream_t stream) {
  const int* x      = (const int*)d_in[0];
  const float* emb  = (const float*)d_in[1];
  const float* qrot = (const float*)d_in[2];
  const float* krot = (const float*)d_in[3];
  const float* vrot = (const float*)d_in[4];
  const float* ffr  = (const float*)d_in[5];
  const float* ffi  = (const float*)d_in[6];
  const float* wr   = (const float*)d_in[7];
  const float* br   = (const float*)d_in[8];
  const float* wi   = (const float*)d_in[9];
  const float* bi   = (const float*)d_in[10];
  float* out = (float*)d_out;
  char* ws = (char*)d_ws;

  unsigned short* Wb = (unsigned short*)ws;                 // 32,768,000 B
  float* bias = (float*)(ws + 32768000);                    //    128,000 B
  float* Sb = (float*)(ws + 32896000);
  float* Qb = Sb + (size_t)ROWS * KK;
  float* Kb = Qb + (size_t)ROWS * KK;
  float* Vb = Kb + (size_t)ROWS * KK;
  float* S2 = Vb + (size_t)ROWS * KK;
  unsigned short* X = (unsigned short*)(S2 + (size_t)ROWS * KK);

  k_prep<<<dim3(VOC * 128 / 256), dim3(256), 0, stream>>>(wr, wi, br, bi, Wb, bias);
  k_embed<<<dim3(ROWS), dim3(256), 0, stream>>>(x, emb, qrot, krot, vrot, Sb, Qb, Kb, Vb);
  k_attn<<<dim3(ROWS), dim3(256), 0, stream>>>(Qb, Kb, Vb, Sb, S2);
  k_ffnorm<<<dim3(ROWS / 4), dim3(256), 0, stream>>>(S2, ffr, ffi, X);
  k_gemm<<<dim3(VOC / 128, ROWS / 128), dim3(256), 0, stream>>>(X, Wb, bias, out);
}